// Round 1
// baseline (399.254 us; speedup 1.0000x reference)
//
#include <hip/hip_runtime.h>
#include <math.h>

// CognitiveRouter: module routing (4) + grouped expert routing (16), combined
// hierarchical probs, top-4 + renorm.  T=32768, D=1536, fp32 in/out.
//
// Structure: lane = row. 256 threads = 4 waves per block, 64 rows/block.
// Each wave accumulates a disjoint 384-col slice of K (split-K within block),
// staging 64x32 hs tiles into a wave-private LDS region (stride 33 -> 2-way
// bank aliasing only, free).  Weight loads are wave-uniform (scalarizable).
// Partials combined through LDS; wave 0 runs the softmax/top-k epilogue.

#define DD 1536
#define NM 4
#define NE 16
#define NW 20          // 16 expert rows + 4 module rows
#define RPB 64         // rows per block
#define CPW 384        // cols per wave (DD / 4 waves)
#define CHUNK 32       // cols staged per iteration
#define LSTRIDE 33     // CHUNK + 1 (bank-conflict pad)
#define WAVE_LDS (RPB * LSTRIDE)  // 2112 floats per wave region

__global__ __launch_bounds__(256)
void router_kernel(const float* __restrict__ hs,
                   const float* __restrict__ Wm,
                   const float* __restrict__ We,
                   float* __restrict__ out,
                   int T)
{
    __shared__ float lds[4 * WAVE_LDS];   // 33792 B
    const int tid  = threadIdx.x;
    const int wv   = tid >> 6;
    const int lane = tid & 63;
    const int rowBlock = blockIdx.x * RPB;
    const int colStart = wv * CPW;

    float acc[NW];
#pragma unroll
    for (int e = 0; e < NW; e++) acc[e] = 0.f;

    // staging map: lane -> (row srow, 4-col group scol); 8 lanes cover 128 B
    // contiguous of one row -> coalesced.
    const int srow = lane >> 3;
    const int scol = (lane & 7) << 2;
    const float* hsBase = hs + (size_t)(rowBlock + srow) * DD + colStart + scol;
    float* myStage = &lds[wv * WAVE_LDS];

    for (int c = 0; c < CPW; c += CHUNK) {
        // ---- stage 64 rows x 32 cols (wave-private region) ----
#pragma unroll
        for (int i = 0; i < 8; i++) {
            float4 v = *(const float4*)(hsBase + (size_t)(i * 8) * DD + c);
            float* dst = &myStage[(srow + i * 8) * LSTRIDE + scol];
            dst[0] = v.x; dst[1] = v.y; dst[2] = v.z; dst[3] = v.w;
        }
        __syncthreads();
        // ---- compute: 8 x 4-col steps, 20 dot-product accumulators ----
#pragma unroll
        for (int g = 0; g < 8; g++) {
            const float* hp = &myStage[lane * LSTRIDE + (g << 2)];
            float h0 = hp[0], h1 = hp[1], h2 = hp[2], h3 = hp[3];
            const int col = colStart + c + (g << 2);
#pragma unroll
            for (int e = 0; e < NE; e++) {
                float4 w4 = *(const float4*)(We + (size_t)e * DD + col);
                acc[e] += h0 * w4.x + h1 * w4.y + h2 * w4.z + h3 * w4.w;
            }
#pragma unroll
            for (int m = 0; m < NM; m++) {
                float4 w4 = *(const float4*)(Wm + (size_t)m * DD + col);
                acc[NE + m] += h0 * w4.x + h1 * w4.y + h2 * w4.z + h3 * w4.w;
            }
        }
        __syncthreads();
    }

    // ---- split-K partial exchange (stride 21: odd -> 2-way aliasing max) ----
#pragma unroll
    for (int e = 0; e < NW; e++) myStage[lane * 21 + e] = acc[e];
    __syncthreads();

    if (wv == 0) {
        float logit[NW];
#pragma unroll
        for (int e = 0; e < NW; e++)
            logit[e] = lds[0 * WAVE_LDS + lane * 21 + e]
                     + lds[1 * WAVE_LDS + lane * 21 + e]
                     + lds[2 * WAVE_LDS + lane * 21 + e]
                     + lds[3 * WAVE_LDS + lane * 21 + e];

        // module softmax over logit[16..19]
        float mmax = logit[16];
#pragma unroll
        for (int m = 1; m < NM; m++) mmax = fmaxf(mmax, logit[16 + m]);
        float mexp[NM], msum = 0.f;
#pragma unroll
        for (int m = 0; m < NM; m++) { mexp[m] = expf(logit[16 + m] - mmax); msum += mexp[m]; }

        // per-module expert softmax, combined probs
        float comb[NE];
#pragma unroll
        for (int m = 0; m < NM; m++) {
            float mprob = mexp[m] / msum;
            float emax = logit[m * 4];
#pragma unroll
            for (int j = 1; j < 4; j++) emax = fmaxf(emax, logit[m * 4 + j]);
            float ee[4], esum = 0.f;
#pragma unroll
            for (int j = 0; j < 4; j++) { ee[j] = expf(logit[m * 4 + j] - emax); esum += ee[j]; }
            float scale = mprob / esum;
#pragma unroll
            for (int j = 0; j < 4; j++) comb[m * 4 + j] = ee[j] * scale;
        }

        const int row = rowBlock + lane;
        float4* cw = (float4*)(out + (size_t)row * 16);
        cw[0] = make_float4(comb[0],  comb[1],  comb[2],  comb[3]);
        cw[1] = make_float4(comb[4],  comb[5],  comb[6],  comb[7]);
        cw[2] = make_float4(comb[8],  comb[9],  comb[10], comb[11]);
        cw[3] = make_float4(comb[12], comb[13], comb[14], comb[15]);

        // top-4, descending, strict > so lowest index wins ties (lax.top_k)
        float tv[4]; int ti[4];
        unsigned mask = 0;
#pragma unroll
        for (int k = 0; k < 4; k++) {
            float best = -1.f; int bi = 0;
#pragma unroll
            for (int i = 0; i < NE; i++) {
                bool avail = !((mask >> i) & 1u);
                if (avail && comb[i] > best) { best = comb[i]; bi = i; }
            }
            tv[k] = best; ti[k] = bi; mask |= 1u << bi;
        }
        float s = tv[0] + tv[1] + tv[2] + tv[3] + 1e-8f;

        const size_t wOff = (size_t)T * 16;          // top_k_weights region
        const size_t iOff = (size_t)T * 20;          // top_k_indices region
        float4* ww = (float4*)(out + wOff + (size_t)row * 4);
        *ww = make_float4(tv[0] / s, tv[1] / s, tv[2] / s, tv[3] / s);
        float4* iw = (float4*)(out + iOff + (size_t)row * 4);
        *iw = make_float4((float)ti[0], (float)ti[1], (float)ti[2], (float)ti[3]);
    }
}

extern "C" void kernel_launch(void* const* d_in, const int* in_sizes, int n_in,
                              void* d_out, int out_size, void* d_ws, size_t ws_size,
                              hipStream_t stream)
{
    const float* hs = (const float*)d_in[0];   // (T, 1536)
    const float* Wm = (const float*)d_in[1];   // (4, 1536)
    const float* We = (const float*)d_in[2];   // (16, 1536)
    float* out = (float*)d_out;
    const int T = in_sizes[0] / DD;            // 32768
    router_kernel<<<T / RPB, 256, 0, stream>>>(hs, Wm, We, out, T);
}